// Round 1
// baseline (532.171 us; speedup 1.0000x reference)
//
#include <hip/hip_runtime.h>
#include <stdint.h>

#define M_DIM 8192
#define K_DIM 4096
#define N_DIM 4096

typedef short short8 __attribute__((ext_vector_type(8)));
typedef unsigned short ushortx8 __attribute__((ext_vector_type(8)));
typedef float floatx4 __attribute__((ext_vector_type(4)));

__device__ __forceinline__ unsigned short f32_to_bf16(float f) {
    union { float f; uint32_t u; } v; v.f = f;
    uint32_t u = v.u;
    return (unsigned short)((u + 0x7fffu + ((u >> 16) & 1u)) >> 16);
}

// async global -> LDS, 16B per lane; lds dest must be wave-uniform base (lane*16 auto)
__device__ __forceinline__ void gload16(const void* g, void* l) {
    __builtin_amdgcn_global_load_lds(
        (const __attribute__((address_space(1))) void*)g,
        (__attribute__((address_space(3))) void*)l,
        16, 0, 0);
}

// ---------------- kernel 1: x fp32 -> bf16 ----------------
__global__ __launch_bounds__(256) void conv_x(const float* __restrict__ x,
                                              unsigned short* __restrict__ xb) {
    size_t base = ((size_t)blockIdx.x * 256 + threadIdx.x) * 8;
    float4 a = *(const float4*)(x + base);
    float4 b = *(const float4*)(x + base + 4);
    ushortx8 o;
    o[0] = f32_to_bf16(a.x); o[1] = f32_to_bf16(a.y);
    o[2] = f32_to_bf16(a.z); o[3] = f32_to_bf16(a.w);
    o[4] = f32_to_bf16(b.x); o[5] = f32_to_bf16(b.y);
    o[6] = f32_to_bf16(b.z); o[7] = f32_to_bf16(b.w);
    *(ushortx8*)(xb + base) = o;
}

// ---------------- kernel 2: dequant + transpose -> Wt [N, K] bf16 ----------------
// qweight [K/8, N] int32 (nibbles along K), qzeros [G, N/8] (nibbles along N),
// scales [G, N], g_idx [K]
#define LROW 272   // 256 + 16 pad elements; keeps 16B alignment, shifts banks
__global__ __launch_bounds__(256) void dequant(const uint32_t* __restrict__ qw,
                                               const uint32_t* __restrict__ qz,
                                               const float* __restrict__ sc,
                                               const int* __restrict__ gidx,
                                               unsigned short* __restrict__ wt) {
    __shared__ __align__(16) unsigned short lds[64 * LROW];
    int tid = threadIdx.x;
    int n0  = blockIdx.x * 64;    // 64 n per block
    int k80 = blockIdx.y * 32;    // 32 packed words = 256 k per block

    #pragma unroll
    for (int i = 0; i < 8; ++i) {
        int idx = i * 256 + tid;          // 0..2047
        int k8l = idx >> 6;               // 0..31
        int nl  = idx & 63;               // 0..63
        int k8  = k80 + k8l;
        int nn  = n0 + nl;
        uint32_t w = qw[(size_t)k8 * N_DIM + nn];
        int g = gidx[k8 * 8];
        uint32_t zw = qz[(size_t)g * (N_DIM / 8) + (nn >> 3)];
        int z = (int)((zw >> ((nn & 7) * 4)) & 0xFu);
        float s = sc[(size_t)g * N_DIM + nn];
        ushortx8 o;
        #pragma unroll
        for (int j = 0; j < 8; ++j) {
            int wv = (int)((w >> (4 * j)) & 0xFu);
            o[j] = f32_to_bf16((float)(wv - z) * s);
        }
        *(ushortx8*)&lds[nl * LROW + k8l * 8] = o;
    }
    __syncthreads();
    #pragma unroll
    for (int i = 0; i < 8; ++i) {
        int idx = i * 256 + tid;
        int row = idx >> 5;               // 0..63  (n within tile)
        int c   = idx & 31;               // 0..31  (16B chunk along k)
        ushortx8 v = *(const ushortx8*)&lds[row * LROW + c * 8];
        *(ushortx8*)&wt[(size_t)(n0 + row) * K_DIM + k80 * 8 + c * 8] = v;
    }
}

// ---------------- kernel 3: bf16 GEMM  C[M,N] = A[M,K] * Wt[N,K]^T ----------------
// 128x128 block tile, BK=32, 256 threads = 4 waves (2x2), each wave 64x64 via
// 4x4 tiles of mfma_f32_16x16x32_bf16. m97-style global_load_lds staging.
__global__ __launch_bounds__(256, 2) void gemm_kernel(const unsigned short* __restrict__ A,
                                                      const unsigned short* __restrict__ B,
                                                      float* __restrict__ C) {
    __shared__ __align__(16) unsigned short As[128 * 32];
    __shared__ __align__(16) unsigned short Bs[128 * 32];

    int tid  = threadIdx.x;
    int lane = tid & 63;
    int wid  = tid >> 6;          // 0..3
    int l15  = lane & 15;
    int quad = lane >> 4;         // 0..3
    int wave_m = wid >> 1;        // 0..1
    int wave_n = wid & 1;         // 0..1

    int bm = blockIdx.y * 128;
    int bn = blockIdx.x * 128;

    // staging: chunk c covers rows [c*16, c*16+16); wave w does chunks w and w+4
    const unsigned short* gA0 = A + (size_t)(bm + wid * 16 + (lane >> 2)) * K_DIM + (lane & 3) * 8;
    const unsigned short* gA1 = gA0 + (size_t)64 * K_DIM;
    const unsigned short* gB0 = B + (size_t)(bn + wid * 16 + (lane >> 2)) * K_DIM + (lane & 3) * 8;
    const unsigned short* gB1 = gB0 + (size_t)64 * K_DIM;
    unsigned short* lA0 = As + wid * 512;
    unsigned short* lA1 = As + (wid + 4) * 512;
    unsigned short* lB0 = Bs + wid * 512;
    unsigned short* lB1 = Bs + (wid + 4) * 512;

    // fragment read offsets (elements): [m_local][k] row-major, BK=32
    int aoff = (wave_m * 64 + l15) * 32 + quad * 8;
    int boff = (wave_n * 64 + l15) * 32 + quad * 8;

    floatx4 acc[4][4];
    #pragma unroll
    for (int i = 0; i < 4; ++i)
        #pragma unroll
        for (int j = 0; j < 4; ++j)
            acc[i][j] = (floatx4){0.f, 0.f, 0.f, 0.f};

    for (int kt = 0; kt < K_DIM; kt += 32) {
        __syncthreads();
        gload16(gA0 + kt, lA0);
        gload16(gA1 + kt, lA1);
        gload16(gB0 + kt, lB0);
        gload16(gB1 + kt, lB1);
        asm volatile("s_waitcnt vmcnt(0)" ::: "memory");
        __syncthreads();

        short8 a[4], b[4];
        #pragma unroll
        for (int t = 0; t < 4; ++t) a[t] = *(const short8*)&As[aoff + t * 512];
        #pragma unroll
        for (int t = 0; t < 4; ++t) b[t] = *(const short8*)&Bs[boff + t * 512];

        #pragma unroll
        for (int mt = 0; mt < 4; ++mt)
            #pragma unroll
            for (int nt = 0; nt < 4; ++nt)
                acc[mt][nt] = __builtin_amdgcn_mfma_f32_16x16x32_bf16(
                    a[mt], b[nt], acc[mt][nt], 0, 0, 0);
    }

    // epilogue: C/D layout col = lane&15 (n), row = quad*4 + reg (m)
    #pragma unroll
    for (int mt = 0; mt < 4; ++mt) {
        int row0 = bm + wave_m * 64 + mt * 16 + quad * 4;
        #pragma unroll
        for (int nt = 0; nt < 4; ++nt) {
            int col = bn + wave_n * 64 + nt * 16 + l15;
            #pragma unroll
            for (int r = 0; r < 4; ++r)
                C[(size_t)(row0 + r) * N_DIM + col] = acc[mt][nt][r];
        }
    }
}

extern "C" void kernel_launch(void* const* d_in, const int* in_sizes, int n_in,
                              void* d_out, int out_size, void* d_ws, size_t ws_size,
                              hipStream_t stream) {
    const float*    x    = (const float*)d_in[0];
    const uint32_t* qw   = (const uint32_t*)d_in[1];
    const uint32_t* qz   = (const uint32_t*)d_in[2];
    const float*    sc   = (const float*)d_in[3];
    const int*      gidx = (const int*)d_in[4];
    float* out = (float*)d_out;

    unsigned short* xb = (unsigned short*)d_ws;                 // [M, K] bf16, 64 MB
    unsigned short* wt = xb + (size_t)M_DIM * K_DIM;            // [N, K] bf16, 32 MB

    conv_x<<<dim3((M_DIM * (size_t)K_DIM) / (256 * 8)), 256, 0, stream>>>(x, xb);
    dequant<<<dim3(N_DIM / 64, K_DIM / 256), 256, 0, stream>>>(qw, qz, sc, gidx, wt);
    gemm_kernel<<<dim3(N_DIM / 128, M_DIM / 128), 256, 0, stream>>>(xb, wt, out);
}

// Round 2
// 389.727 us; speedup vs baseline: 1.3655x; 1.3655x over previous
//
#include <hip/hip_runtime.h>
#include <stdint.h>

#define M_DIM 8192
#define K_DIM 4096
#define N_DIM 4096

typedef int   i32x4 __attribute__((ext_vector_type(4)));
typedef float f32x4 __attribute__((ext_vector_type(4)));

// async global -> LDS, 16B per active lane; LDS dest = wave-uniform base + lane*16
__device__ __forceinline__ void gload16(const void* g, void* l) {
    __builtin_amdgcn_global_load_lds(
        (const __attribute__((address_space(1))) void*)g,
        (__attribute__((address_space(3))) void*)l,
        16, 0, 0);
}

// ---------------- kernel 1: x fp32 -> int8 with per-row scale ----------------
// one block (256 thr) per row of 4096; xq int8 [M][K], xs fp32 [M]
__global__ __launch_bounds__(256) void conv_x_i8(const float* __restrict__ x,
                                                 int* __restrict__ xq,
                                                 float* __restrict__ xs) {
    int m = blockIdx.x, tid = threadIdx.x;
    const float* row = x + (size_t)m * K_DIM;
    float4 v[4];
    float mx = 0.f;
    #pragma unroll
    for (int i = 0; i < 4; ++i) {
        v[i] = *(const float4*)(row + i * 1024 + tid * 4);
        mx = fmaxf(mx, fmaxf(fmaxf(fabsf(v[i].x), fabsf(v[i].y)),
                             fmaxf(fabsf(v[i].z), fabsf(v[i].w))));
    }
    #pragma unroll
    for (int o = 32; o > 0; o >>= 1) mx = fmaxf(mx, __shfl_xor(mx, o, 64));
    __shared__ float red[4];
    if ((tid & 63) == 0) red[tid >> 6] = mx;
    __syncthreads();
    mx = fmaxf(fmaxf(red[0], red[1]), fmaxf(red[2], red[3]));
    mx = fmaxf(mx, 1e-20f);
    float inv = 127.f / mx;
    if (tid == 0) xs[m] = mx * (1.f / 127.f);
    #pragma unroll
    for (int i = 0; i < 4; ++i) {
        int q0 = (int)__builtin_rintf(v[i].x * inv);
        int q1 = (int)__builtin_rintf(v[i].y * inv);
        int q2 = (int)__builtin_rintf(v[i].z * inv);
        int q3 = (int)__builtin_rintf(v[i].w * inv);
        uint32_t p = (uint32_t)(q0 & 255) | ((uint32_t)(q1 & 255) << 8) |
                     ((uint32_t)(q2 & 255) << 16) | ((uint32_t)q3 << 24);
        xq[(size_t)m * (K_DIM / 4) + i * 256 + tid] = (int)p;
    }
}

// ---------------- kernel 2: dequant -> Wt int8 [N, K], value (w - z) ----------------
#define DLROW 272   // 256 + 16 bytes pad
__global__ __launch_bounds__(256) void dequant_i8(const uint32_t* __restrict__ qw,
                                                  const uint32_t* __restrict__ qz,
                                                  const int* __restrict__ gidx,
                                                  signed char* __restrict__ wt) {
    __shared__ __align__(16) unsigned char lds[64 * DLROW];
    int tid = threadIdx.x;
    int n0  = blockIdx.x * 64;    // 64 n per block
    int k80 = blockIdx.y * 32;    // 32 packed words = 256 k per block

    #pragma unroll
    for (int i = 0; i < 8; ++i) {
        int idx = i * 256 + tid;          // 0..2047
        int k8l = idx >> 6;               // 0..31
        int nl  = idx & 63;               // 0..63
        int k8  = k80 + k8l;
        int nn  = n0 + nl;
        uint32_t w = qw[(size_t)k8 * N_DIM + nn];
        int g = gidx[k8 * 8];
        uint32_t zw = qz[(size_t)g * (N_DIM / 8) + (nn >> 3)];
        int z = (int)((zw >> ((nn & 7) * 4)) & 0xFu);
        uint64_t o = 0;
        #pragma unroll
        for (int j = 0; j < 8; ++j) {
            int wv = (int)((w >> (4 * j)) & 0xFu);
            o |= (uint64_t)(uint8_t)(signed char)(wv - z) << (8 * j);
        }
        *(uint64_t*)&lds[nl * DLROW + k8l * 8] = o;
    }
    __syncthreads();
    #pragma unroll
    for (int i = 0; i < 4; ++i) {
        int idx = i * 256 + tid;          // 1024 chunk tasks
        int row = idx >> 4;               // 0..63
        int c   = idx & 15;               // 16B chunk along k
        i32x4 v = *(const i32x4*)&lds[row * DLROW + c * 16];
        *(i32x4*)&wt[(size_t)(n0 + row) * K_DIM + k80 * 8 + c * 16] = v;
    }
}

// ---------------- kernel 3: int8 GEMM with per-group rescale ----------------
// C[M,N] = xs[m] * sum_g s[g,n] * (xq[m,:] . wt[n,:])_int over k-group g (128 k)
// 128x128 block tile, BK=128 (= one group), 4 waves 2x2, wave 64x64 via 4x4
// tiles of mfma_i32_16x16x64_i8 (2 chained k-steps per group).
// LDS rows 128 B; 16B chunks XOR-swizzled by (row&7) for bank spread.
__global__ __launch_bounds__(256, 2) void gemm_i8(const signed char* __restrict__ A,
                                                  const signed char* __restrict__ B,
                                                  const float* __restrict__ S,
                                                  const float* __restrict__ XS,
                                                  float* __restrict__ C) {
    __shared__ __align__(16) signed char As[128 * 128];
    __shared__ __align__(16) signed char Bs[128 * 128];
    __shared__ __align__(16) float Ss[128];

    int tid  = threadIdx.x;
    int lane = tid & 63;
    int wid  = tid >> 6;          // 0..3
    int l15  = lane & 15;
    int quad = lane >> 4;         // 0..3
    int wave_m = wid >> 1;
    int wave_n = wid & 1;

    int bm = blockIdx.y * 128;
    int bn = blockIdx.x * 128;

    // staging: round i covers rows i*32..i*32+31; thread t: row = i*32 + (t>>3),
    // LDS slot = t&7, global chunk = slot ^ (row & 7)
    int srow   = tid >> 3;                 // 0..31
    int gchunk = (tid & 7) ^ (srow & 7);
    const signed char* gA = A + (size_t)(bm + srow) * K_DIM + gchunk * 16;
    const signed char* gB = B + (size_t)(bn + srow) * K_DIM + gchunk * 16;

    f32x4 facc[4][4];
    #pragma unroll
    for (int i = 0; i < 4; ++i)
        #pragma unroll
        for (int j = 0; j < 4; ++j)
            facc[i][j] = (f32x4){0.f, 0.f, 0.f, 0.f};

    const i32x4 zi = (i32x4){0, 0, 0, 0};
    int h = l15 & 7;   // swizzle key for fragment reads (row&7 == l15&7)

    for (int kt = 0; kt < K_DIM; kt += 128) {
        __syncthreads();
        #pragma unroll
        for (int i = 0; i < 4; ++i) {
            gload16(gA + kt + (size_t)i * 32 * K_DIM, As + i * 4096 + wid * 1024);
            gload16(gB + kt + (size_t)i * 32 * K_DIM, Bs + i * 4096 + wid * 1024);
        }
        if (tid < 32)
            gload16(S + ((size_t)(kt >> 7) * N_DIM + bn + tid * 4), Ss);
        asm volatile("s_waitcnt vmcnt(0)" ::: "memory");
        __syncthreads();

        float sv[4];
        #pragma unroll
        for (int nt = 0; nt < 4; ++nt)
            sv[nt] = Ss[wave_n * 64 + nt * 16 + l15];

        i32x4 bf[4][2];
        #pragma unroll
        for (int nt = 0; nt < 4; ++nt) {
            int brow = wave_n * 64 + nt * 16 + l15;
            bf[nt][0] = *(const i32x4*)&Bs[brow * 128 + ((quad) ^ h) * 16];
            bf[nt][1] = *(const i32x4*)&Bs[brow * 128 + ((4 + quad) ^ h) * 16];
        }

        #pragma unroll
        for (int mt = 0; mt < 4; ++mt) {
            int arow = wave_m * 64 + mt * 16 + l15;
            i32x4 a0 = *(const i32x4*)&As[arow * 128 + ((quad) ^ h) * 16];
            i32x4 a1 = *(const i32x4*)&As[arow * 128 + ((4 + quad) ^ h) * 16];
            #pragma unroll
            for (int nt = 0; nt < 4; ++nt) {
                i32x4 iacc = __builtin_amdgcn_mfma_i32_16x16x64_i8(a0, bf[nt][0], zi, 0, 0, 0);
                iacc = __builtin_amdgcn_mfma_i32_16x16x64_i8(a1, bf[nt][1], iacc, 0, 0, 0);
                #pragma unroll
                for (int r = 0; r < 4; ++r)
                    facc[mt][nt][r] += (float)iacc[r] * sv[nt];
            }
        }
    }

    // epilogue: C/D layout col = lane&15 (n), row = quad*4 + r (m)
    #pragma unroll
    for (int mt = 0; mt < 4; ++mt) {
        int row0 = bm + wave_m * 64 + mt * 16 + quad * 4;
        float4 xsv = *(const float4*)(XS + row0);
        #pragma unroll
        for (int nt = 0; nt < 4; ++nt) {
            int col = bn + wave_n * 64 + nt * 16 + l15;
            C[(size_t)(row0 + 0) * N_DIM + col] = facc[mt][nt][0] * xsv.x;
            C[(size_t)(row0 + 1) * N_DIM + col] = facc[mt][nt][1] * xsv.y;
            C[(size_t)(row0 + 2) * N_DIM + col] = facc[mt][nt][2] * xsv.z;
            C[(size_t)(row0 + 3) * N_DIM + col] = facc[mt][nt][3] * xsv.w;
        }
    }
}

extern "C" void kernel_launch(void* const* d_in, const int* in_sizes, int n_in,
                              void* d_out, int out_size, void* d_ws, size_t ws_size,
                              hipStream_t stream) {
    const float*    x    = (const float*)d_in[0];
    const uint32_t* qw   = (const uint32_t*)d_in[1];
    const uint32_t* qz   = (const uint32_t*)d_in[2];
    const float*    sc   = (const float*)d_in[3];
    const int*      gidx = (const int*)d_in[4];
    float* out = (float*)d_out;

    signed char* xq = (signed char*)d_ws;                          // [M][K] int8, 32 MB
    signed char* wt = xq + (size_t)M_DIM * K_DIM;                  // [N][K] int8, 16 MB
    float*       xs = (float*)(wt + (size_t)N_DIM * K_DIM);        // [M] fp32

    conv_x_i8<<<dim3(M_DIM), 256, 0, stream>>>(x, (int*)xq, xs);
    dequant_i8<<<dim3(N_DIM / 64, K_DIM / 256), 256, 0, stream>>>(qw, qz, gidx, wt);
    gemm_i8<<<dim3(N_DIM / 128, M_DIM / 128), 256, 0, stream>>>(xq, wt, sc, xs, out);
}